// Round 7
// baseline (1801.108 us; speedup 1.0000x reference)
//
#include <hip/hip_runtime.h>
#include <hip/hip_bf16.h>

#define NLAY 8
#define MFMA __builtin_amdgcn_mfma_f32_16x16x32_bf16

typedef __attribute__((ext_vector_type(8))) short bf16x8;
typedef __attribute__((ext_vector_type(4))) float f32x4;
typedef __attribute__((ext_vector_type(4))) int i32x4;

template <bool BF16>
__device__ __forceinline__ float ld(const void* p, int i) {
  if (BF16) {
    unsigned short u = ((const unsigned short*)p)[i];
    return __uint_as_float(((unsigned)u) << 16);
  }
  return ((const float*)p)[i];
}

template <bool BF16>
__device__ __forceinline__ float2 ld2(const void* p, int i) {  // i even
  float2 r;
  if (BF16) {
    unsigned u = ((const unsigned*)p)[i >> 1];
    r.x = __uint_as_float(u << 16);
    r.y = __uint_as_float(u & 0xffff0000u);
  } else {
    r = ((const float2*)p)[i >> 1];
  }
  return r;
}

__device__ __forceinline__ float bfu(unsigned short u) {
  return __uint_as_float(((unsigned)u) << 16);
}

__device__ __forceinline__ unsigned short bfpack(float v) {
  __hip_bfloat16 h = __float2bfloat16(v);
  unsigned short u;
  __builtin_memcpy(&u, &h, 2);
  return u;
}

__device__ __forceinline__ unsigned pack_bf2(float a, float b) {
  return ((unsigned)bfpack(b) << 16) | (unsigned)bfpack(a);
}

__device__ __forceinline__ float2 unpk(unsigned u) {
  float2 r;
  r.x = __uint_as_float(u << 16);
  r.y = __uint_as_float(u & 0xffff0000u);
  return r;
}

__device__ __forceinline__ bf16x8 as_bf(i32x4 v) {
  union { i32x4 i; bf16x8 b; } u;
  u.i = v;
  return u.b;
}

// ws[0..271]=sin, ws[272..543]=cos, ws[544..1699]=dmask, ws[1700]=dtype flag
__global__ void setup_tables(float* __restrict__ ws, const void* __restrict__ x) {
  int tid = threadIdx.x;
  for (int idx = tid; idx < 272; idx += 256) {
    int t = idx >> 4, j = idx & 15;
    float a = powf(10000.f, -(float)(j >> 1) / 7.f);
    float arg = (float)t * a;
    ws[idx] = sinf(arg);
    ws[272 + idx] = cosf(arg);
  }
  for (int row = tid; row < 68; row += 256) {
    int hh = row / 17, t = row % 17;
    float gamma = 1.f - exp2f(-5.f - 4.f * (float)hh / 3.f);
    float sum = 0.f;
    for (int u = 0; u <= t; ++u) sum += powf(gamma, (float)(t - u));
    float rn = rsqrtf(sum);
    for (int u = 0; u < 17; ++u)
      ws[544 + row * 17 + u] = (u <= t) ? powf(gamma, (float)(t - u)) * rn : 0.f;
  }
  if (tid == 0) {
    const unsigned short* u16 = (const unsigned short*)x;
    int sane = 0;
    for (int i = 0; i < 128; ++i) {
      float v = __uint_as_float(((unsigned)u16[2 * i]) << 16);
      float av = fabsf(v);
      if (v == 0.f || (av > 1e-8f && av < 1e4f)) sane++;
    }
    ws[1700] = (sane >= 64) ? 1.f : 0.f;
  }
}

// FR layout (ushort): patch B-frags [0,12288); per layer (35840) at 12288+l*35840:
//   Wq 4096 | Wk 4096 | Wv 8192 | Wg 8192 | Wo 8192 | w1f 1024 | w2f 2048
#define FRAG_TOT 299008
template <bool BF16>
__global__ void prep_frags(const void* __restrict__ patch_w,
                           const void* __restrict__ Wq, const void* __restrict__ Wk,
                           const void* __restrict__ Wv, const void* __restrict__ Wg,
                           const void* __restrict__ Wo, const void* __restrict__ w1,
                           const void* __restrict__ w2,
                           const float* __restrict__ tab,
                           unsigned short* __restrict__ frag) {
  if ((tab[1700] > 0.5f) != BF16) return;
  int g = blockIdx.x * 256 + threadIdx.x;
  if (g >= FRAG_TOT) return;
  float v;
  if (g < 12288) {  // patch_w: K=192 (kt6), N=64 (nt4)
    int nt = g / 3072, r = g % 3072, kt = r / 512, r2 = r % 512, la = r2 >> 3, j = r2 & 7;
    int n = nt * 16 + (la & 15), k = kt * 32 + (la >> 4) * 8 + j;
    v = ld<BF16>(patch_w, k * 64 + n);
  } else {
    int gg = g - 12288, l = gg / 35840, o = gg % 35840;
    if (o < 8192) {  // Wq / Wk: N=64 K=64
      const void* W = (o < 4096) ? Wq : Wk;
      int e = o & 4095;
      int nt = e / 1024, r = e % 1024, kt = r / 512, r2 = r % 512, la = r2 >> 3, j = r2 & 7;
      int n = nt * 16 + (la & 15), k = kt * 32 + (la >> 4) * 8 + j;
      v = ld<BF16>(W, l * 4096 + k * 64 + n);
    } else if (o < 24576) {  // Wv / Wg: N=128 K=64
      const void* W = (o < 16384) ? Wv : Wg;
      int e = (o - 8192) & 8191;
      int nt = e / 1024, r = e % 1024, kt = r / 512, r2 = r % 512, la = r2 >> 3, j = r2 & 7;
      int n = nt * 16 + (la & 15), k = kt * 32 + (la >> 4) * 8 + j;
      v = ld<BF16>(W, l * 8192 + k * 128 + n);
    } else if (o < 32768) {  // Wo: N=64 K=128
      int e = o - 24576;
      int nt = e / 2048, r = e % 2048, kt = r / 512, r2 = r % 512, la = r2 >> 3, j = r2 & 7;
      int n = nt * 16 + (la & 15), k = kt * 32 + (la >> 4) * 8 + j;
      v = ld<BF16>(Wo, l * 8192 + k * 64 + n);
    } else if (o < 33792) {  // w1f: B[n=e][k=d], N=12(pad16) K=64
      int e = o - 32768;
      int kt = e / 512, r2 = e % 512, la = r2 >> 3, j = r2 & 7;
      int n = la & 15, k = kt * 32 + (la >> 4) * 8 + j;
      v = (n < 12) ? ld<BF16>(w1, l * 768 + k * 12 + n) : 0.f;
    } else {  // w2f: B[n=d][k=e], N=64 K=12(pad32)
      int e = o - 33792;
      int nt = e / 512, r2 = e % 512, la = r2 >> 3, j = r2 & 7;
      int n = nt * 16 + (la & 15), k = (la >> 4) * 8 + j;
      v = (k < 12) ? ld<BF16>(w2, l * 768 + k * 64 + n) : 0.f;
    }
  }
  frag[g] = bfpack(v);
}

// LDS float offsets (SM_TOT 19740 = 78.9 KB -> 2 blocks/CU)
#define O_ST   0      // 512: lnMu[34] lnR[34] den[136] gnMu[136] gnR[136]
#define O_H    512    // 2244: H fp32 34x66
#define O_XNF  2756   // 1536: XN A-frags; O fp32 (34x130=4420) aliases 2756..7176
#define O_QB   4292   // 1224: Q hi bf16 [34][72]
#define O_QL   5516   // 1224: Q lo
#define O_KB   6740   // 1224: K hi
#define O_KL   7964   // 1224: K lo
#define O_FFH  9188   // 272: gelu hi bf16 [34][16]
#define O_FFL  9460   // 272: gelu lo
#define O_OAF  9732   // 3072: OA frags / patch A-frags at start
#define O_VB   12804  // 2312: V bf16 [34][136]
#define O_GB   15116  // 2312: G bf16 [34][136]
#define O_SCH  17428  // 1088: scores hi bf16 [136][16]
#define O_SCL  18516  // 1088: scores lo
#define O_S16  19604  // 136: t=16 score rows fp32 [2][4][17]
#define SM_TOT 19740

template <bool BF16>
__global__ void __launch_bounds__(512)
vit_fused(const void* __restrict__ x, const void* __restrict__ patch_b,
          const void* __restrict__ cls, const void* __restrict__ pos,
          const void* __restrict__ ln1s, const void* __restrict__ ln1b,
          const void* __restrict__ b1, const void* __restrict__ b2,
          const void* __restrict__ ln2s, const void* __restrict__ ln2b,
          const void* __restrict__ lnfs, const void* __restrict__ lnfb,
          const void* __restrict__ neckw, const void* __restrict__ neckb,
          const void* __restrict__ headw, const void* __restrict__ headb,
          const float* __restrict__ tab,
          const unsigned short* __restrict__ FR, void* __restrict__ out) {
  if ((tab[1700] > 0.5f) != BF16) return;

  const int tid = threadIdx.x;
  const int lane = tid & 63, w = tid >> 6;  // w 0..7
  const int lq = lane >> 4, ln = lane & 15;
  const int img0 = 2 * blockIdx.x;

  __shared__ __align__(16) float sm[SM_TOT];
  float* sST  = sm + O_ST;
  float* sH   = sm + O_H;
  float* sO   = sm + O_XNF;  // fp32 34x130, aliases XNF/Qb/Ql/Kb-head
  float* sS16 = sm + O_S16;
  unsigned short* sQb  = (unsigned short*)(sm + O_QB);
  unsigned short* sQl  = (unsigned short*)(sm + O_QL);
  unsigned short* sKb  = (unsigned short*)(sm + O_KB);
  unsigned short* sKl  = (unsigned short*)(sm + O_KL);
  unsigned short* sFFh = (unsigned short*)(sm + O_FFH);
  unsigned short* sFFl = (unsigned short*)(sm + O_FFL);
  unsigned short* sSCh = (unsigned short*)(sm + O_SCH);
  unsigned short* sSCl = (unsigned short*)(sm + O_SCL);
  unsigned short* sVb  = (unsigned short*)(sm + O_VB);
  unsigned short* sGb  = (unsigned short*)(sm + O_GB);
  const bf16x8* FRB = (const bf16x8*)FR;
  const float* tabSin = tab;
  const float* tabCos = tab + 272;
  const float* tabDM  = tab + 544;
  const f32x4 fz = {0.f, 0.f, 0.f, 0.f};

  // ---- startup: zero FF pads, stage patch A-frags, cls rows ----
  for (int i = tid; i < 544; i += 512) ((unsigned*)(sm + O_FFH))[i] = 0;
  for (int s = tid; s < 768; s += 512) {  // patch A-frags into O_OAF
    int mt = s / 384, r = s % 384, kt = r / 64, la = r % 64;
    int p = la & 15, q = la >> 4;
    int kb = kt * 32 + q * 8;
    int c = kb >> 6, rem = kb & 63, a = rem >> 3;
    int pi = p >> 2, pj = p & 3;
    int src = (img0 + mt) * 3072 + c * 1024 + (pi * 8 + a) * 32 + pj * 8;
    float v[8];
#pragma unroll
    for (int t2 = 0; t2 < 8; t2 += 2) {
      float2 pv = ld2<BF16>(x, src + t2);
      v[t2] = pv.x; v[t2 + 1] = pv.y;
    }
    i32x4 pk;
    pk.x = pack_bf2(v[0], v[1]); pk.y = pack_bf2(v[2], v[3]);
    pk.z = pack_bf2(v[4], v[5]); pk.w = pack_bf2(v[6], v[7]);
    ((i32x4*)(sm + O_OAF))[s] = pk;
  }
  if (tid < 128) {
    int img = tid >> 6, n = tid & 63;
    sH[(img * 17) * 66 + n] = ld<BF16>(cls, n) + ld<BF16>(pos, n);
  }
  __syncthreads();

  // ---- patch embed MFMA: 8 jobs ----
  {
    int mt = w >> 2, nt = w & 3;
    f32x4 acc = fz;
    const bf16x8* paf = (const bf16x8*)(sm + O_OAF);
#pragma unroll
    for (int kt = 0; kt < 6; ++kt)
      acc = MFMA(paf[(mt * 6 + kt) * 64 + lane], FRB[(nt * 6 + kt) * 64 + lane], acc, 0, 0, 0);
    int n = nt * 16 + ln;
    float pb = ld<BF16>(patch_b, n);
#pragma unroll
    for (int i = 0; i < 4; ++i) {
      int t = 1 + lq * 4 + i;
      sH[(mt * 17 + t) * 66 + n] = acc[i] + pb + ld<BF16>(pos, t * 64 + n);
    }
  }
  __syncthreads();

  for (int l = 0; l < NLAY; ++l) {
    const int LB8 = 1536 + l * 4480;  // layer base in bf16x8 units

    // ---- ln1 stats ----
    if (tid < 272) {
      int m = tid >> 3, sub = tid & 7;
      const float* hp = sH + m * 66 + sub * 8;
      float s1 = 0.f, s2 = 0.f;
#pragma unroll
      for (int i = 0; i < 8; ++i) { float v = hp[i]; s1 += v; s2 += v * v; }
      s1 += __shfl_xor(s1, 1); s2 += __shfl_xor(s2, 1);
      s1 += __shfl_xor(s1, 2); s2 += __shfl_xor(s2, 2);
      s1 += __shfl_xor(s1, 4); s2 += __shfl_xor(s2, 4);
      if (sub == 0) {
        float mu = s1 * (1.f / 64.f);
        float var = s2 * (1.f / 64.f) - mu * mu;
        sST[m] = mu;
        sST[34 + m] = rsqrtf(var + 1e-5f);
      }
    }
    __syncthreads();

    // ---- ln1 -> XN A-frags ----
    for (int s = tid; s < 384; s += 512) {
      int mt = s >> 7, kt = (s >> 6) & 1, la = s & 63;
      int m = mt * 16 + (la & 15), q = la >> 4;
      int kb = kt * 32 + q * 8;
      i32x4 pk = {0, 0, 0, 0};
      if (m < 34) {
        float mu = sST[m], rr = sST[34 + m];
        float vv[8];
#pragma unroll
        for (int t2 = 0; t2 < 8; t2 += 2) {
          float2 sv = ld2<BF16>(ln1s, l * 64 + kb + t2);
          float2 bv = ld2<BF16>(ln1b, l * 64 + kb + t2);
          vv[t2]     = (sH[m * 66 + kb + t2] - mu) * rr * sv.x + bv.x;
          vv[t2 + 1] = (sH[m * 66 + kb + t2 + 1] - mu) * rr * sv.y + bv.y;
        }
        pk.x = pack_bf2(vv[0], vv[1]); pk.y = pack_bf2(vv[2], vv[3]);
        pk.z = pack_bf2(vv[4], vv[5]); pk.w = pack_bf2(vv[6], vv[7]);
      }
      ((i32x4*)(sm + O_XNF))[s] = pk;
    }
    __syncthreads();

    // ---- QKVG MFMA (72 jobs); rotary in-register; Q/K stored hi+lo ----
    {
      const bf16x8* xnf = (const bf16x8*)(sm + O_XNF);
      const int jjc = ln & 14;
      for (int j = w; j < 72; j += 8) {
        int mt = j / 24, nt = j % 24;
        const bf16x8* wf; int ntl, dst;
        if (nt < 4)       { wf = FRB + LB8;        ntl = nt;      dst = 0; }
        else if (nt < 8)  { wf = FRB + LB8 + 512;  ntl = nt - 4;  dst = 1; }
        else if (nt < 16) { wf = FRB + LB8 + 1024; ntl = nt - 8;  dst = 2; }
        else              { wf = FRB + LB8 + 2048; ntl = nt - 16; dst = 3; }
        f32x4 acc = fz;
#pragma unroll
        for (int kt = 0; kt < 2; ++kt)
          acc = MFMA(xnf[(mt * 2 + kt) * 64 + lane], wf[(ntl * 2 + kt) * 64 + lane], acc, 0, 0, 0);
        int n = ntl * 16 + ln;
        if (dst <= 1) {
          float scale = dst ? 0.25f : 1.f;
          unsigned short* Dh = dst ? sKb : sQb;
          unsigned short* Dl = dst ? sKl : sQl;
#pragma unroll
          for (int i = 0; i < 4; ++i) {
            int m = mt * 16 + lq * 4 + i;
            float p = __shfl_xor(acc[i], 1);  // rotary partner d^1, same m
            int img = (m >= 17) ? 1 : 0;
            int t = m - img * 17;
            if (t > 16) t = 16;  // clamp for pad rows
            float cv = tabCos[t * 16 + jjc], sv = tabSin[t * 16 + jjc];
            float v = (ln & 1) ? (cv * acc[i] + sv * p) : (cv * acc[i] - sv * p);
            v *= scale;
            if (m < 34) {
              unsigned short hv = bfpack(v);
              Dh[m * 72 + n] = hv;
              Dl[m * 72 + n] = bfpack(v - bfu(hv));
            }
          }
        } else {
          unsigned short* db = (dst == 2) ? sVb : sGb;
#pragma unroll
          for (int i = 0; i < 4; ++i) {
            int m = mt * 16 + lq * 4 + i;
            if (m < 34) db[m * 136 + n] = bfpack(acc[i]);
          }
        }
      }
    }
    __syncthreads();

    // ---- scores MFMA (t<16,u<16): 8 jobs x 3 MFMAs (hi/lo cross terms) ----
    {
      int img = w >> 2, hh = w & 3;
      i32x4 ah = {0,0,0,0}, al = {0,0,0,0}, bh = {0,0,0,0}, bl = {0,0,0,0};
      int rq = (img * 17 + ln) * 72 + hh * 16 + lq * 8;
      if (lq < 2) {
        ah = *(const i32x4*)(sQb + rq);
        al = *(const i32x4*)(sQl + rq);
        bh = *(const i32x4*)(sKb + rq);
        bl = *(const i32x4*)(sKl + rq);
      }
      f32x4 acc = MFMA(as_bf(ah), as_bf(bh), fz, 0, 0, 0);
      acc = MFMA(as_bf(ah), as_bf(bl), acc, 0, 0, 0);
      acc = MFMA(as_bf(al), as_bf(bh), acc, 0, 0, 0);
      int base = (img * 4 + hh) * 17;
#pragma unroll
      for (int i = 0; i < 4; ++i) {
        int t = lq * 4 + i;
        float dm = tabDM[hh * 289 + t * 17 + ln];  // zero for u>t
        float p = acc[i] * dm;
        unsigned short ph = bfpack(p);
        sSCh[(base + t) * 16 + ln] = ph;
        sSCl[(base + t) * 16 + ln] = bfpack(p - bfu(ph));
      }
    }
    if (tid < 136) {  // t=16 row, fp32, u 0..16
      int img = tid / 68, rr = tid % 68, hh = rr / 17, u = rr % 17;
      const unsigned* qh = (const unsigned*)(sQb + (img * 17 + 16) * 72 + hh * 16);
      const unsigned* ql = (const unsigned*)(sQl + (img * 17 + 16) * 72 + hh * 16);
      const unsigned* kh = (const unsigned*)(sKb + (img * 17 + u) * 72 + hh * 16);
      const unsigned* kl = (const unsigned*)(sKl + (img * 17 + u) * 72 + hh * 16);
      float acc = 0.f;
#pragma unroll
      for (int p = 0; p < 8; ++p) {
        float2 qhv = unpk(qh[p]), qlv = unpk(ql[p]);
        float2 khv = unpk(kh[p]), klv = unpk(kl[p]);
        acc += (qhv.x + qlv.x) * (khv.x + klv.x) + (qhv.y + qlv.y) * (khv.y + klv.y);
      }
      acc *= tabDM[hh * 289 + 272 + u];
      sS16[(img * 4 + hh) * 17 + u] = acc;
    }
    __syncthreads();

    // ---- denominators ----
    if (tid < 136) {
      int t = tid % 17;
      float s = 0.f;
      if (t < 16) {
        const unsigned* ph = (const unsigned*)(sSCh + tid * 16);
        const unsigned* pl = (const unsigned*)(sSCl + tid * 16);
#pragma unroll
        for (int p = 0; p < 8; ++p) {
          float2 h = unpk(ph[p]), lo = unpk(pl[p]);
          s += h.x + lo.x + h.y + lo.y;
        }
      } else {
        const float* p16 = sS16 + (tid - 16);
#pragma unroll
        for (int u = 0; u < 17; ++u) s += p16[u];
      }
      float den = fabsf(s);
      if (den < 1.f) den = 1.f;
      sST[68 + tid] = 1.f / den;
    }
    __syncthreads();

    // ---- AV: 16 jobs x 2 MFMAs (P hi/lo); t=16 row VALU fp32 ----
    for (int j = w; j < 16; j += 8) {
      int img = j >> 3, hh = (j >> 1) & 3, ntl = j & 1;
      int row = (img * 4 + hh) * 17 + ln;  // ln = t' 0..15
      i32x4 ah = {0,0,0,0}, al = {0,0,0,0};
      if (lq < 2) {
        ah = *(const i32x4*)(sSCh + row * 16 + lq * 8);
        al = *(const i32x4*)(sSCl + row * 16 + lq * 8);
      }
      int c = hh * 32 + ntl * 16 + ln;
      unsigned bw[4];
#pragma unroll
      for (int h2 = 0; h2 < 4; ++h2) {
        int u0 = lq * 8 + h2 * 2, u1 = u0 + 1;
        unsigned short v0 = (u0 < 17) ? sVb[(img * 17 + u0) * 136 + c] : (unsigned short)0;
        unsigned short v1 = (u1 < 17) ? sVb[(img * 17 + u1) * 136 + c] : (unsigned short)0;
        bw[h2] = (unsigned)v0 | ((unsigned)v1 << 16);
      }
      i32x4 bi; bi.x = bw[0]; bi.y = bw[1]; bi.z = bw[2]; bi.w = bw[3];
      f32x4 acc = MFMA(as_bf(ah), as_bf(bi), fz, 0, 0, 0);
      acc = MFMA(as_bf(al), as_bf(bi), acc, 0, 0, 0);
#pragma unroll
      for (int i = 0; i < 4; ++i) {
        int t = lq * 4 + i;
        float dinv = sST[68 + (img * 4 + hh) * 17 + t];
        sO[(img * 17 + t) * 130 + c] = acc[i] * dinv;
      }
    }
    if (tid < 256) {  // t=16 AV row
      int img = tid >> 7, c = tid & 127, hh = c >> 5;
      int rb = (img * 4 + hh) * 17;
      float acc = 0.f;
#pragma unroll
      for (int u = 0; u <= 16; ++u)
        acc += sS16[rb + u] * bfu(sVb[(img * 17 + u) * 136 + c]);
      acc *= sST[68 + rb + 16];
      sO[(img * 17 + 16) * 130 + c] = acc;
    }
    __syncthreads();

    // ---- group norm stats ----
    if (tid < 272) {
      int row = tid >> 1, sub = tid & 1;
      int img = row / 68, hr = row % 68, hh = hr / 17, t = hr % 17;
      int m = img * 17 + t;
      const float* op = sO + m * 130 + hh * 32 + sub * 16;
      float s1 = 0.f, s2 = 0.f;
#pragma unroll
      for (int i = 0; i < 16; ++i) { float v = op[i]; s1 += v; s2 += v * v; }
      s1 += __shfl_xor(s1, 1); s2 += __shfl_xor(s2, 1);
      if (sub == 0) {
        float mu = s1 * (1.f / 32.f);
        float var = s2 * (1.f / 32.f) - mu * mu;
        sST[204 + row] = mu;
        sST[340 + row] = rsqrtf(var + 1e-5f);
      }
    }
    __syncthreads();

    // ---- groupnorm + silu gate -> OA frags ----
    for (int s = tid; s < 768; s += 512) {
      int mt = s >> 8, kt = (s >> 6) & 3, la = s & 63;
      int q = la >> 4, m = mt * 16 + (la & 15);
      int cb = kt * 32 + q * 8;
      i32x4 pk = {0, 0, 0, 0};
      if (m < 34) {
        int img = (m >= 17), t = m - img * 17;
        int sti = img * 68 + kt * 17 + t;
        float mu = sST[204 + sti], rr = sST[340 + sti];
        float vv[8];
#pragma unroll
        for (int q2 = 0; q2 < 8; ++q2) {
          int c = cb + q2;
          float on = (sO[m * 130 + c] - mu) * rr;
          float gv = bfu(sGb[m * 136 + c]);
          vv[q2] = on * (gv / (1.f + __expf(-gv)));
        }
        pk.x = pack_bf2(vv[0], vv[1]); pk.y = pack_bf2(vv[2], vv[3]);
        pk.z = pack_bf2(vv[4], vv[5]); pk.w = pack_bf2(vv[6], vv[7]);
      }
      ((i32x4*)(sm + O_OAF))[s] = pk;
    }
    __syncthreads();

    // ---- Wo MFMA: 12 jobs; += residual ----
    {
      const bf16x8* oaf = (const bf16x8*)(sm + O_OAF);
      const bf16x8* wof = FRB + LB8 + 3072;
      for (int j = w; j < 12; j += 8) {
        int mt = j / 4, nt = j % 4;
        f32x4 acc = fz;
#pragma unroll
        for (int kt = 0; kt < 4; ++kt)
          acc = MFMA(oaf[(mt * 4 + kt) * 64 + lane], wof[(nt * 4 + kt) * 64 + lane], acc, 0, 0, 0);
        int n = nt * 16 + ln;
#pragma unroll
        for (int i = 0; i < 4; ++i) {
          int m = mt * 16 + lq * 4 + i;
          if (m < 34) sH[m * 66 + n] += acc[i];
        }
      }
    }
    __syncthreads();

    // ---- ln2 stats ----
    if (tid < 272) {
      int m = tid >> 3, sub = tid & 7;
      const float* hp = sH + m * 66 + sub * 8;
      float s1 = 0.f, s2 = 0.f;
#pragma unroll
      for (int i = 0; i < 8; ++i) { float v = hp[i]; s1 += v; s2 += v * v; }
      s1 += __shfl_xor(s1, 1); s2 += __shfl_xor(s2, 1);
      s1 += __shfl_xor(s1, 2); s2 += __shfl_xor(s2, 2);
      s1 += __shfl_xor(s1, 4); s2 += __shfl_xor(s2, 4);
      if (sub == 0) {
        float mu = s1 * (1.f / 64.f);
        float var = s2 * (1.f / 64.f) - mu * mu;
        sST[m] = mu;
        sST[34 + m] = rsqrtf(var + 1e-5f);
      }
    }
    __syncthreads();

    // ---- ln2 -> XN A-frags (O dead) ----
    for (int s = tid; s < 384; s += 512) {
      int mt = s >> 7, kt = (s >> 6) & 1, la = s & 63;
      int m = mt * 16 + (la & 15), q = la >> 4;
      int kb = kt * 32 + q * 8;
      i32x4 pk = {0, 0, 0, 0};
      if (m < 34) {
        float mu = sST[m], rr = sST[34 + m];
        float vv[8];
#pragma unroll
        for (int t2 = 0; t2 < 8; t2 += 2) {
          float2 sv = ld2<BF16>(ln2s, l * 64 + kb + t2);
          float2 bv = ld2<BF16>(ln2b, l * 64 + kb + t2);
          vv[t2]     = (sH[m * 66 + kb + t2] - mu) * rr * sv.x + bv.x;
          vv[t2 + 1] = (sH[m * 66 + kb + t2 + 1] - mu) * rr * sv.y + bv.y;
        }
        pk.x = pack_bf2(vv[0], vv[1]); pk.y = pack_bf2(vv[2], vv[3]);
        pk.z = pack_bf2(vv[4], vv[5]); pk.w = pack_bf2(vv[6], vv[7]);
      }
      ((i32x4*)(sm + O_XNF))[s] = pk;
    }
    __syncthreads();

    // ---- FFN1 MFMA: 3 jobs; gelu -> hi/lo ----
    {
      const bf16x8* xnf = (const bf16x8*)(sm + O_XNF);
      for (int mt = w; mt < 3; mt += 8) {
        f32x4 acc = fz;
#pragma unroll
        for (int kt = 0; kt < 2; ++kt)
          acc = MFMA(xnf[(mt * 2 + kt) * 64 + lane], FRB[LB8 + 4096 + kt * 64 + lane], acc, 0, 0, 0);
        int e = ln;
        if (e < 12) {
          float bb = ld<BF16>(b1, l * 12 + e);
#pragma unroll
          for (int i = 0; i < 4; ++i) {
            int m = mt * 16 + lq * 4 + i;
            if (m < 34) {
              float a = acc[i] + bb;
              float inner = 0.7978845608028654f * (a + 0.044715f * a * a * a);
              float g = 0.5f * a * (1.f + tanhf(inner));
              unsigned short gh = bfpack(g);
              sFFh[m * 16 + e] = gh;
              sFFl[m * 16 + e] = bfpack(g - bfu(gh));
            }
          }
        }
      }
    }
    __syncthreads();

    // ---- FFN2: 12 jobs x 2 MFMAs (hi/lo); += residual + b2 ----
    for (int j = w; j < 12; j += 8) {
      int mt = j / 4, nt = j % 4;
      i32x4 ah = {0,0,0,0}, al = {0,0,0,0};
      if (lq < 2) {
        ah = *(const i32x4*)(sFFh + (mt * 16 + ln) * 16 + lq * 8);
        al = *(const i32x4*)(sFFl + (mt * 16 + ln) * 16 + lq * 8);
      }
      bf16x8 wv = FRB[LB8 + 4224 + nt * 64 + lane];
      f32x4 acc = MFMA(as_bf(ah), wv, fz, 0, 0, 0);
      acc = MFMA(as_bf(al), wv, acc, 0, 0, 0);
      int n = nt * 16 + ln;
      float bb = ld<BF16>(b2, l * 64 + n);
#pragma unroll
      for (int i = 0; i < 4; ++i) {
        int m = mt * 16 + lq * 4 + i;
        if (m < 34) sH[m * 66 + n] += acc[i] + bb;
      }
    }
    __syncthreads();
  }

  // ---- final: lnf (last token each image), neck, head ----
  if (tid < 2) {
    int m = tid * 17 + 16;
    float s1 = 0.f, s2 = 0.f;
    for (int d = 0; d < 64; ++d) {
      float v = sH[m * 66 + d];
      s1 += v; s2 += v * v;
    }
    float mu = s1 * (1.f / 64.f);
    float var = s2 * (1.f / 64.f) - mu * mu;
    sST[tid] = mu;
    sST[2 + tid] = rsqrtf(var + 1e-5f);
  }
  __syncthreads();
  if (tid < 32) {
    int img = tid >> 4, jn = tid & 15;
    int m = img * 17 + 16;
    float mu = sST[img], rr = sST[2 + img];
    float acc = ld<BF16>(neckb, jn);
    for (int d = 0; d < 64; ++d) {
      float yn = (sH[m * 66 + d] - mu) * rr * ld<BF16>(lnfs, d) + ld<BF16>(lnfb, d);
      acc += yn * ld<BF16>(neckw, d * 16 + jn);
    }
    sST[8 + img * 16 + jn] = acc;
  }
  __syncthreads();
  if (tid < 20) {
    int img = tid / 10, o = tid % 10;
    float acc = ld<BF16>(headb, o);
#pragma unroll
    for (int e = 0; e < 16; ++e) acc += sST[8 + img * 16 + e] * ld<BF16>(headw, e * 10 + o);
    if (BF16) {
      ((__hip_bfloat16*)out)[(img0 + img) * 10 + o] = __float2bfloat16(acc);
    } else {
      ((float*)out)[(img0 + img) * 10 + o] = acc;
    }
  }
}

extern "C" void kernel_launch(void* const* d_in, const int* in_sizes, int n_in,
                              void* d_out, int out_size, void* d_ws, size_t ws_size,
                              hipStream_t stream) {
  float* tab = (float*)d_ws;
  unsigned short* frag = (unsigned short*)((char*)d_ws + 8192);

  setup_tables<<<dim3(1), dim3(256), 0, stream>>>(tab, d_in[0]);

  const int prepBlocks = (FRAG_TOT + 255) / 256;
  prep_frags<false><<<dim3(prepBlocks), dim3(256), 0, stream>>>(
      d_in[1], d_in[5], d_in[6], d_in[7], d_in[8], d_in[9], d_in[12], d_in[14], tab, frag);
  prep_frags<true><<<dim3(prepBlocks), dim3(256), 0, stream>>>(
      d_in[1], d_in[5], d_in[6], d_in[7], d_in[8], d_in[9], d_in[12], d_in[14], tab, frag);

  const int B = in_sizes[0] / 3072;
  const int grid = B / 2;

  vit_fused<false><<<dim3(grid), dim3(512), 0, stream>>>(
      d_in[0], d_in[2], d_in[3], d_in[4], d_in[10], d_in[11], d_in[13],
      d_in[15], d_in[16], d_in[17], d_in[18], d_in[19], d_in[20], d_in[21],
      d_in[22], d_in[23], tab, frag, d_out);
  vit_fused<true><<<dim3(grid), dim3(512), 0, stream>>>(
      d_in[0], d_in[2], d_in[3], d_in[4], d_in[10], d_in[11], d_in[13],
      d_in[15], d_in[16], d_in[17], d_in[18], d_in[19], d_in[20], d_in[21],
      d_in[22], d_in[23], tab, frag, d_out);
}